// Round 4
// baseline (502.038 us; speedup 1.0000x reference)
//
#include <hip/hip_runtime.h>
#include <cstdint>
#include <cstddef>

#define D_MODEL 2048
#define EPSF 1e-5f

// workspace layout (float offsets)
#define WS_UT    0          // u/h transposed [4][8][4096] = 131072
#define WS_MU1   131072     // [16384]
#define WS_RSIG1 147456     // [16384]
#define WS_WDT   163840     // gamma-folded W_down^T [32][2048] = 65536
#define WS_WINF  229376     // gamma-folded W_in [2048][8] = 16384
#define WS_C     245760     // [32]  col-sums gamma*Wd
#define WS_D     245792     // [32]  col-sums beta*Wd + bd
#define WS_CIN   245824     // [8]   col-sums gamma*Win
#define WS_DIN   245832     // [8]   col-sums beta*Win + b_in

__device__ __forceinline__ float4 ld4(const float* __restrict__ p) {
    return *(const float4*)p;
}
__device__ __forceinline__ void st4(float* __restrict__ p, float4 v) {
    *(float4*)p = v;
}
__device__ __forceinline__ int bitrev6(int l) {
    return ((l & 1) << 5) | ((l & 2) << 3) | ((l & 4) << 1) |
           ((l & 8) >> 1) | ((l & 16) >> 3) | ((l & 32) >> 5);
}
__device__ __forceinline__ int bitrev4(int l) {
    return ((l & 1) << 3) | ((l & 2) << 1) | ((l & 4) >> 1) | ((l & 8) >> 3);
}

// ---------------------------------------------------------------------------
// K0: weight prep. blocks 0..7: gamma-folded W_down^T via LDS transpose.
// block 8: c/d col-sums for Wd. block 9: gamma-folded W_in + cin/din.
// ---------------------------------------------------------------------------
__global__ __launch_bounds__(64) void k0_prep(
    const float* __restrict__ Win, const float* __restrict__ b_in,
    const float* __restrict__ Wd, const float* __restrict__ gamma,
    const float* __restrict__ beta, const float* __restrict__ bd,
    float* __restrict__ ws)
{
    const int t = threadIdx.x;
    const int blk = blockIdx.x;
    if (blk < 8) {
        __shared__ float tile[64 * 33];
        const int gblk = blk;               // i-range [gblk*256, gblk*256+256)
        for (int cc = 0; cc < 4; ++cc) {
            const int ibase = gblk * 256 + cc * 64;
#pragma unroll
            for (int m = 0; m < 32; ++m) {
                const int e = m * 64 + t;   // linear within 64x32 chunk, coalesced
                const int il = e >> 5, j = e & 31;
                tile[il * 33 + j] = Wd[(size_t)ibase * 32 + e];
            }
            __syncthreads();
#pragma unroll
            for (int j = 0; j < 32; ++j) {
                const int i = ibase + t;
                ws[WS_WDT + (size_t)j * 2048 + i] = gamma[i] * tile[t * 33 + j];
            }
            __syncthreads();
        }
    } else if (blk == 8) {
        const int j = t & 31, h = t >> 5;
        float cacc = 0.f, dacc = 0.f;
        for (int k = 0; k < 1024; ++k) {
            const int i = h * 1024 + k;
            const float w = Wd[(size_t)i * 32 + j];
            cacc = fmaf(gamma[i], w, cacc);
            dacc = fmaf(beta[i], w, dacc);
        }
        cacc += __shfl_xor(cacc, 32, 64);
        dacc += __shfl_xor(dacc, 32, 64);
        if (t < 32) {
            ws[WS_C + j] = cacc;
            ws[WS_D + j] = dacc + bd[j];
        }
    } else {
        // fold Winf[i][j] = gamma_i * Win[i][j]; cin_j, din_j col-sums
        float cj[8], dj[8];
#pragma unroll
        for (int j = 0; j < 8; ++j) { cj[j] = 0.f; dj[j] = 0.f; }
        for (int k = 0; k < 32; ++k) {
            const int i = k * 64 + t;
            const float g = gamma[i], b = beta[i];
            float4 w0 = ld4(Win + (size_t)i * 8);
            float4 w1 = ld4(Win + (size_t)i * 8 + 4);
            st4(ws + WS_WINF + (size_t)i * 8,
                make_float4(g * w0.x, g * w0.y, g * w0.z, g * w0.w));
            st4(ws + WS_WINF + (size_t)i * 8 + 4,
                make_float4(g * w1.x, g * w1.y, g * w1.z, g * w1.w));
            cj[0] = fmaf(g, w0.x, cj[0]); cj[1] = fmaf(g, w0.y, cj[1]);
            cj[2] = fmaf(g, w0.z, cj[2]); cj[3] = fmaf(g, w0.w, cj[3]);
            cj[4] = fmaf(g, w1.x, cj[4]); cj[5] = fmaf(g, w1.y, cj[5]);
            cj[6] = fmaf(g, w1.z, cj[6]); cj[7] = fmaf(g, w1.w, cj[7]);
            dj[0] = fmaf(b, w0.x, dj[0]); dj[1] = fmaf(b, w0.y, dj[1]);
            dj[2] = fmaf(b, w0.z, dj[2]); dj[3] = fmaf(b, w0.w, dj[3]);
            dj[4] = fmaf(b, w1.x, dj[4]); dj[5] = fmaf(b, w1.y, dj[5]);
            dj[6] = fmaf(b, w1.z, dj[6]); dj[7] = fmaf(b, w1.w, dj[7]);
        }
#pragma unroll
        for (int off = 1; off < 64; off <<= 1) {
#pragma unroll
            for (int j = 0; j < 8; ++j) {
                cj[j] += __shfl_xor(cj[j], off, 64);
                dj[j] += __shfl_xor(dj[j], off, 64);
            }
        }
        if (t == 0) {
#pragma unroll
            for (int j = 0; j < 8; ++j) {
                ws[WS_CIN + j] = cj[j];
                ws[WS_DIN + j] = dj[j] + b_in[j];
            }
        }
    }
}

// ---------------------------------------------------------------------------
// K1: 8 rows/block, software-pipelined (prefetch row rr+1 while reducing rr)
// to keep live regs < 128 (no spills). Per row: 10 partials (sum, ssq, 8 uraw)
// reduced in one 16-value split-butterfly. 1 barrier per block.
// ---------------------------------------------------------------------------
__global__ __launch_bounds__(256, 4) void k1_ln_u(
    const float* __restrict__ x, float* __restrict__ ws)
{
    __shared__ float red[8][4][12];
    const int t = threadIdx.x;
    const int wv = t >> 6, lane = t & 63;
    const int row0 = blockIdx.x * 8;
    const int i0 = t * 8;

    float winf[64];
#pragma unroll
    for (int q = 0; q < 16; ++q) {
        float4 v = ld4(ws + WS_WINF + (size_t)i0 * 8 + q * 4);
        winf[q*4+0] = v.x; winf[q*4+1] = v.y; winf[q*4+2] = v.z; winf[q*4+3] = v.w;
    }
    float4 xa = ld4(x + (size_t)row0 * D_MODEL + i0);
    float4 xb = ld4(x + (size_t)row0 * D_MODEL + i0 + 4);
#pragma unroll 1
    for (int rr = 0; rr < 8; ++rr) {
        float xc[8];
        xc[0]=xa.x; xc[1]=xa.y; xc[2]=xa.z; xc[3]=xa.w;
        xc[4]=xb.x; xc[5]=xb.y; xc[6]=xb.z; xc[7]=xb.w;
        if (rr < 7) {
            const float* xr = x + (size_t)(row0 + rr + 1) * D_MODEL + i0;
            xa = ld4(xr);
            xb = ld4(xr + 4);
        }
        float vals[16];
#pragma unroll
        for (int v = 0; v < 16; ++v) vals[v] = 0.f;
#pragma unroll
        for (int i = 0; i < 8; ++i) {
            const float xi = xc[i];
            vals[0] += xi;
            vals[1] = fmaf(xi, xi, vals[1]);
#pragma unroll
            for (int j = 0; j < 8; ++j)
                vals[2+j] = fmaf(xi, winf[i*8 + j], vals[2+j]);
        }
        // 16-value split-butterfly over 64 lanes
        int count = 16;
#pragma unroll
        for (int step = 1; step <= 32; step <<= 1) {
            if (count > 1) {
                const int half = count >> 1;
                const bool up = (lane & step) != 0;
#pragma unroll
                for (int k = 0; k < 8; ++k) {
                    if (k < half) {
                        float send = vals[up ? k : k + half];
                        float keep = vals[up ? k + half : k];
                        vals[k] = keep + __shfl_xor(send, step, 64);
                    }
                }
                count = half;
            } else {
                vals[0] += __shfl_xor(vals[0], step, 64);
            }
        }
        if (lane < 16) {
            const int v = bitrev4(lane);
            if (v < 10) red[rr][wv][v] = vals[0];
        }
    }
    __syncthreads();
    if (t < 64) {
        const int row = t >> 3, j = t & 7;
        float s_ = 0.f, q_ = 0.f, uraw = 0.f;
#pragma unroll
        for (int w = 0; w < 4; ++w) {
            s_   += red[row][w][0];
            q_   += red[row][w][1];
            uraw += red[row][w][2 + j];
        }
        const float mu = s_ * (1.f / D_MODEL);
        const float var = q_ * (1.f / D_MODEL) - mu * mu;
        const float rs = rsqrtf(var + EPSF);
        const float u = fmaf(rs, fmaf(-mu, ws[WS_CIN + j], uraw), ws[WS_DIN + j]);
        const int grow = row0 + row;
        const int bb = grow >> 12, s0 = grow & 4095;
        ws[WS_UT + ((size_t)bb * 8 + j) * 4096 + s0] = u;
        if (j == 0) {
            ws[WS_MU1 + grow] = mu;
            ws[WS_RSIG1 + grow] = rs;
        }
    }
}

// ---------------------------------------------------------------------------
// K2: decay scan per (b,r), in place over u (chunked + wave Kogge-Stone)
// ---------------------------------------------------------------------------
__global__ __launch_bounds__(64) void k2_scan(
    const float* __restrict__ logit, float* __restrict__ ws)
{
    const int t = threadIdx.x;
    const int blk = blockIdx.x;
    const int b = blk >> 3, r = blk & 7;
    const float a = 1.f / (1.f + expf(-logit[r]));
    float* u = ws + WS_UT + ((size_t)b * 8 + r) * 4096 + t * 64;
    float v[64];
#pragma unroll
    for (int q = 0; q < 16; ++q) {
        float4 w = ld4(u + q * 4);
        v[q*4]=w.x; v[q*4+1]=w.y; v[q*4+2]=w.z; v[q*4+3]=w.w;
    }
    float c = 0.f;
#pragma unroll
    for (int k = 0; k < 64; ++k) { c = fmaf(a, c, v[k]); v[k] = c; }
    float A = a;
#pragma unroll
    for (int i = 0; i < 6; ++i) A *= A;   // a^64
    float Bv = c, Aa = A;
#pragma unroll
    for (int off = 1; off < 64; off <<= 1) {
        float Ap = __shfl_up(Aa, off, 64);
        float Bp = __shfl_up(Bv, off, 64);
        if (t >= off) { Bv = fmaf(Aa, Bp, Bv); Aa *= Ap; }
    }
    float P = __shfl_up(Bv, 1, 64);
    if (t == 0) P = 0.f;
    float f = a * P;
#pragma unroll
    for (int k = 0; k < 64; ++k) { v[k] += f; f *= a; }
#pragma unroll
    for (int q = 0; q < 16; ++q)
        st4(u + q * 4, make_float4(v[q*4], v[q*4+1], v[q*4+2], v[q*4+3]));
}

// ---------------------------------------------------------------------------
// K3: fused tail, 8 rows/block, col-owned phase A.
// Phase A: thread owns cols {c0, c0+1024}; Wout slice in regs (read once per
//          block); x2 -> LDS Y; batched LN2 stats (one 16-value butterfly).
// Phase B: praw = x2 @ WDT, wave owns j-octet, double-buffered WDT prefetch;
//          split-butterfly-64 reduce; fused LN2 affine + ReLU -> shf.
// Phase C: out = x2 + bu + hf @ Wu, double-buffered Wu prefetch, single write.
// ---------------------------------------------------------------------------
__global__ __launch_bounds__(256, 2) void k3_fused(
    const float* __restrict__ x, const float* __restrict__ gamma,
    const float* __restrict__ beta, const float* __restrict__ Wout,
    const float* __restrict__ b_out, const float* __restrict__ Dsk,
    const float* __restrict__ Wu, const float* __restrict__ bu,
    float* __restrict__ out, float* __restrict__ ws)
{
    __shared__ float Y[8 * 2048];   // 64 KiB: x2 rows
    __shared__ float sh_h[8][8];
    __shared__ float smu1[8], srs1[8];
    __shared__ float smu2[8], srs2[8];
    __shared__ float red2[16][4];
    __shared__ float shf[8 * 32];
    const int t = threadIdx.x;
    const int blk = blockIdx.x;
    const int row0 = blk * 8;
    const int wv = t >> 6, lane = t & 63;

    if (t < 64) {
        const int r_ = t >> 3, j_ = t & 7;
        const int grow = row0 + r_;
        const int bb = grow >> 12, s = grow & 4095;
        sh_h[r_][j_] = ws[WS_UT + ((size_t)bb * 8 + j_) * 4096 + s];
        if (j_ == 0) {
            smu1[r_] = ws[WS_MU1 + grow];
            srs1[r_] = ws[WS_RSIG1 + grow];
        }
    }
    __syncthreads();

    // copy h to regs (broadcast b128 LDS reads)
    float hreg[64];
#pragma unroll
    for (int r = 0; r < 8; ++r) {
        float4 h0 = ld4(&sh_h[r][0]);
        float4 h1 = ld4(&sh_h[r][4]);
        hreg[r*8+0]=h0.x; hreg[r*8+1]=h0.y; hreg[r*8+2]=h0.z; hreg[r*8+3]=h0.w;
        hreg[r*8+4]=h1.x; hreg[r*8+5]=h1.y; hreg[r*8+6]=h1.z; hreg[r*8+7]=h1.w;
    }

    float sum[8], ssq[8];
#pragma unroll
    for (int r = 0; r < 8; ++r) { sum[r] = 0.f; ssq[r] = 0.f; }

#pragma unroll 1
    for (int pass = 0; pass < 2; ++pass) {
        const int c = pass * 1024 + t * 4;
        const float4 g = ld4(gamma + c), bt = ld4(beta + c);
        const float4 bo = ld4(b_out + c), dk = ld4(Dsk + c);
        float4 wo[8];
#pragma unroll
        for (int j = 0; j < 8; ++j) wo[j] = ld4(Wout + (size_t)j * D_MODEL + c);
#pragma unroll
        for (int r = 0; r < 8; ++r) {
            const float4 xv = ld4(x + (size_t)(row0 + r) * D_MODEL + c);
            const float mu1 = smu1[r], rs1 = srs1[r];
            float4 acc = bo;
#pragma unroll
            for (int j = 0; j < 8; ++j) {
                const float hj = hreg[r*8 + j];
                acc.x = fmaf(hj, wo[j].x, acc.x);
                acc.y = fmaf(hj, wo[j].y, acc.y);
                acc.z = fmaf(hj, wo[j].z, acc.z);
                acc.w = fmaf(hj, wo[j].w, acc.w);
            }
            float4 xn;
            xn.x = fmaf((xv.x - mu1) * rs1, g.x, bt.x);
            xn.y = fmaf((xv.y - mu1) * rs1, g.y, bt.y);
            xn.z = fmaf((xv.z - mu1) * rs1, g.z, bt.z);
            xn.w = fmaf((xv.w - mu1) * rs1, g.w, bt.w);
            acc.x = fmaf(xn.x, dk.x, acc.x);
            acc.y = fmaf(xn.y, dk.y, acc.y);
            acc.z = fmaf(xn.z, dk.z, acc.z);
            acc.w = fmaf(xn.w, dk.w, acc.w);
            float4 x2;
            x2.x = xv.x + acc.x; x2.y = xv.y + acc.y;
            x2.z = xv.z + acc.z; x2.w = xv.w + acc.w;
            st4(&Y[r * 2048 + c], x2);
            sum[r] += x2.x + x2.y + x2.z + x2.w;
            ssq[r] = fmaf(x2.x, x2.x, ssq[r]); ssq[r] = fmaf(x2.y, x2.y, ssq[r]);
            ssq[r] = fmaf(x2.z, x2.z, ssq[r]); ssq[r] = fmaf(x2.w, x2.w, ssq[r]);
        }
    }
    // batched LN2 reduce: 16 values (sum[0..8), ssq[0..8))
    {
        float vals[16];
#pragma unroll
        for (int r = 0; r < 8; ++r) { vals[r] = sum[r]; vals[8+r] = ssq[r]; }
        int count = 16;
#pragma unroll
        for (int step = 1; step <= 32; step <<= 1) {
            if (count > 1) {
                const int half = count >> 1;
                const bool up = (lane & step) != 0;
#pragma unroll
                for (int k = 0; k < 8; ++k) {
                    if (k < half) {
                        float send = vals[up ? k : k + half];
                        float keep = vals[up ? k + half : k];
                        vals[k] = keep + __shfl_xor(send, step, 64);
                    }
                }
                count = half;
            } else {
                vals[0] += __shfl_xor(vals[0], step, 64);
            }
        }
        if (lane < 16) red2[bitrev4(lane)][wv] = vals[0];
    }
    __syncthreads();
    if (t < 8) {
        float s_ = red2[t][0] + red2[t][1] + red2[t][2] + red2[t][3];
        float q_ = red2[8+t][0] + red2[8+t][1] + red2[8+t][2] + red2[8+t][3];
        const float mu2 = s_ * (1.f / D_MODEL);
        const float var = q_ * (1.f / D_MODEL) - mu2 * mu2;
        smu2[t] = mu2;
        srs2[t] = rsqrtf(var + EPSF);
    }
    __syncthreads();

    // Phase B: wave wv owns j-octet [8wv, 8wv+8)
    const int jb = wv * 8;
    float p[64];
#pragma unroll
    for (int v = 0; v < 64; ++v) p[v] = 0.f;
    float4 wb[8], wbn[8];
#pragma unroll
    for (int jj = 0; jj < 8; ++jj)
        wb[jj] = ld4(ws + WS_WDT + (size_t)(jb + jj) * 2048 + lane * 4);
#pragma unroll 1
    for (int q = 0; q < 8; ++q) {
        const int ip = q * 256 + lane * 4;
        if (q < 7) {
#pragma unroll
            for (int jj = 0; jj < 8; ++jj)
                wbn[jj] = ld4(ws + WS_WDT + (size_t)(jb + jj) * 2048 + ip + 256);
        }
        float4 yv[8];
#pragma unroll
        for (int rr = 0; rr < 8; ++rr) yv[rr] = ld4(&Y[rr * 2048 + ip]);
#pragma unroll
        for (int jj = 0; jj < 8; ++jj) {
#pragma unroll
            for (int rr = 0; rr < 8; ++rr) {
                p[rr*8+jj] = fmaf(yv[rr].x, wb[jj].x, p[rr*8+jj]);
                p[rr*8+jj] = fmaf(yv[rr].y, wb[jj].y, p[rr*8+jj]);
                p[rr*8+jj] = fmaf(yv[rr].z, wb[jj].z, p[rr*8+jj]);
                p[rr*8+jj] = fmaf(yv[rr].w, wb[jj].w, p[rr*8+jj]);
            }
        }
#pragma unroll
        for (int jj = 0; jj < 8; ++jj) wb[jj] = wbn[jj];
    }
    // split-butterfly reduce: lane ends with total for v = bitrev6(lane)
    {
        int count = 64;
#pragma unroll
        for (int step = 1; step <= 32; step <<= 1) {
            const int half = count >> 1;
            const bool up = (lane & step) != 0;
#pragma unroll
            for (int k = 0; k < 32; ++k) {
                if (k < half) {
                    float send = p[up ? k : k + half];
                    float keep = p[up ? k + half : k];
                    p[k] = keep + __shfl_xor(send, step, 64);
                }
            }
            count = half;
        }
    }
    {
        const int v = bitrev6(lane);
        const int r_ = v >> 3, j_ = v & 7;
        const float mu2r = smu2[r_], rs2r = srs2[r_];
        const float cj = ws[WS_C + jb + j_], dj = ws[WS_D + jb + j_];
        shf[r_ * 32 + jb + j_] =
            fmaxf(0.f, fmaf(rs2r, fmaf(-mu2r, cj, p[0]), dj));
    }
    __syncthreads();

    // Phase C: thread owns cols c0=t*4 and c0+1024 for all 8 rows
    const int c0 = t * 4;
    float4 a0[8], a1[8];
    const float4 bu0 = ld4(bu + c0), bu1 = ld4(bu + 1024 + c0);
#pragma unroll
    for (int rr = 0; rr < 8; ++rr) {
        float4 y0 = ld4(&Y[rr * 2048 + c0]);
        float4 y1 = ld4(&Y[rr * 2048 + 1024 + c0]);
        a0[rr] = make_float4(y0.x + bu0.x, y0.y + bu0.y, y0.z + bu0.z, y0.w + bu0.w);
        a1[rr] = make_float4(y1.x + bu1.x, y1.y + bu1.y, y1.z + bu1.z, y1.w + bu1.w);
    }
    float4 w0[4], w1[4], w0n[4], w1n[4];
#pragma unroll
    for (int jj = 0; jj < 4; ++jj) {
        w0[jj] = ld4(Wu + (size_t)jj * D_MODEL + c0);
        w1[jj] = ld4(Wu + (size_t)jj * D_MODEL + 1024 + c0);
    }
#pragma unroll 1
    for (int jc = 0; jc < 8; ++jc) {
        if (jc < 7) {
#pragma unroll
            for (int jj = 0; jj < 4; ++jj) {
                w0n[jj] = ld4(Wu + (size_t)((jc+1)*4 + jj) * D_MODEL + c0);
                w1n[jj] = ld4(Wu + (size_t)((jc+1)*4 + jj) * D_MODEL + 1024 + c0);
            }
        }
        float4 hq[8];
#pragma unroll
        for (int rr = 0; rr < 8; ++rr) hq[rr] = ld4(&shf[rr * 32 + jc * 4]);
#pragma unroll
        for (int jj = 0; jj < 4; ++jj) {
#pragma unroll
            for (int rr = 0; rr < 8; ++rr) {
                const float hval = (jj == 0) ? hq[rr].x : (jj == 1) ? hq[rr].y
                                 : (jj == 2) ? hq[rr].z : hq[rr].w;
                a0[rr].x = fmaf(hval, w0[jj].x, a0[rr].x);
                a0[rr].y = fmaf(hval, w0[jj].y, a0[rr].y);
                a0[rr].z = fmaf(hval, w0[jj].z, a0[rr].z);
                a0[rr].w = fmaf(hval, w0[jj].w, a0[rr].w);
                a1[rr].x = fmaf(hval, w1[jj].x, a1[rr].x);
                a1[rr].y = fmaf(hval, w1[jj].y, a1[rr].y);
                a1[rr].z = fmaf(hval, w1[jj].z, a1[rr].z);
                a1[rr].w = fmaf(hval, w1[jj].w, a1[rr].w);
            }
        }
#pragma unroll
        for (int jj = 0; jj < 4; ++jj) { w0[jj] = w0n[jj]; w1[jj] = w1n[jj]; }
    }
#pragma unroll
    for (int rr = 0; rr < 8; ++rr) {
        float* orow = out + (size_t)(row0 + rr) * D_MODEL;
        st4(orow + c0, a0[rr]);
        st4(orow + 1024 + c0, a1[rr]);
    }
}

// ---------------------------------------------------------------------------
extern "C" void kernel_launch(void* const* d_in, const int* in_sizes, int n_in,
                              void* d_out, int out_size, void* d_ws, size_t ws_size,
                              hipStream_t stream) {
    const float* x      = (const float*)d_in[0];
    const float* gamma  = (const float*)d_in[1];
    const float* beta   = (const float*)d_in[2];
    const float* Win    = (const float*)d_in[3];
    const float* b_in   = (const float*)d_in[4];
    const float* logit  = (const float*)d_in[5];
    const float* Wout   = (const float*)d_in[6];
    const float* b_out  = (const float*)d_in[7];
    const float* Dsk    = (const float*)d_in[8];
    const float* Wd     = (const float*)d_in[9];
    const float* bd     = (const float*)d_in[10];
    const float* Wu     = (const float*)d_in[11];
    const float* bu     = (const float*)d_in[12];
    float* out = (float*)d_out;
    float* ws  = (float*)d_ws;

    hipLaunchKernelGGL(k0_prep, dim3(10),   dim3(64),  0, stream,
                       Win, b_in, Wd, gamma, beta, bd, ws);
    hipLaunchKernelGGL(k1_ln_u, dim3(2048), dim3(256), 0, stream, x, ws);
    hipLaunchKernelGGL(k2_scan, dim3(32),   dim3(64),  0, stream, logit, ws);
    hipLaunchKernelGGL(k3_fused, dim3(2048), dim3(256), 0, stream,
                       x, gamma, beta, Wout, b_out, Dsk, Wu, bu, out, ws);
}

// Round 5
// 464.731 us; speedup vs baseline: 1.0803x; 1.0803x over previous
//
#include <hip/hip_runtime.h>
#include <cstdint>
#include <cstddef>

#define D_MODEL 2048
#define EPSF 1e-5f

// workspace layout (float offsets)
#define WS_UT    0          // u/h transposed [4][8][4096] = 131072
#define WS_MU1   131072     // [16384]
#define WS_RSIG1 147456     // [16384]
#define WS_WDT   163840     // gamma-folded W_down^T [32][2048] = 65536
#define WS_WINF  229376     // gamma-folded W_in [2048][8] = 16384
#define WS_C     245760     // [32]  col-sums gamma*Wd
#define WS_D     245792     // [32]  col-sums beta*Wd + bd
#define WS_CIN   245824     // [8]   col-sums gamma*Win
#define WS_DIN   245832     // [8]   col-sums beta*Win + b_in
#define WS_CP    245840     // [8][64] partial c (0..31) / d (32..63) per gblk

__device__ __forceinline__ float4 ld4(const float* __restrict__ p) {
    return *(const float4*)p;
}
__device__ __forceinline__ void st4(float* __restrict__ p, float4 v) {
    *(float4*)p = v;
}
__device__ __forceinline__ int bitrev6(int l) {
    return ((l & 1) << 5) | ((l & 2) << 3) | ((l & 4) << 1) |
           ((l & 8) >> 1) | ((l & 16) >> 3) | ((l & 32) >> 5);
}
__device__ __forceinline__ int bitrev4(int l) {
    return ((l & 1) << 3) | ((l & 2) << 1) | ((l & 4) >> 1) | ((l & 8) >> 3);
}

// ---------------------------------------------------------------------------
// K0: weight prep. blocks 0..7: gamma-folded W_down^T via LDS transpose +
// PARTIAL c/d column sums from the staged tile (no serial global chain).
// block 8: gamma-folded W_in + cin/din.
// ---------------------------------------------------------------------------
__global__ __launch_bounds__(64) void k0_prep(
    const float* __restrict__ Win, const float* __restrict__ b_in,
    const float* __restrict__ Wd, const float* __restrict__ gamma,
    const float* __restrict__ beta, const float* __restrict__ bd,
    float* __restrict__ ws)
{
    const int t = threadIdx.x;
    const int blk = blockIdx.x;
    if (blk < 8) {
        __shared__ float tile[64 * 33];
        __shared__ float sg[64], sb[64];
        float part = 0.f;                   // c-partial (t<32, j=t) or d-partial
        for (int cc = 0; cc < 4; ++cc) {
            const int ibase = blk * 256 + cc * 64;
#pragma unroll
            for (int m = 0; m < 32; ++m) {
                const int e = m * 64 + t;   // linear within 64x32 chunk, coalesced
                const int il = e >> 5, j = e & 31;
                tile[il * 33 + j] = Wd[(size_t)ibase * 32 + e];
            }
            sg[t] = gamma[ibase + t];
            sb[t] = beta[ibase + t];
            __syncthreads();
#pragma unroll
            for (int j = 0; j < 32; ++j)
                ws[WS_WDT + (size_t)j * 2048 + ibase + t] = sg[t] * tile[t * 33 + j];
            // partial c/d from LDS tile (4 independent accumulators)
            {
                const int j = t & 31;
                const float* wvec = (t < 32) ? sg : sb;
                float a0 = 0.f, a1 = 0.f, a2 = 0.f, a3 = 0.f;
#pragma unroll
                for (int il = 0; il < 64; il += 4) {
                    a0 = fmaf(wvec[il+0], tile[(il+0) * 33 + j], a0);
                    a1 = fmaf(wvec[il+1], tile[(il+1) * 33 + j], a1);
                    a2 = fmaf(wvec[il+2], tile[(il+2) * 33 + j], a2);
                    a3 = fmaf(wvec[il+3], tile[(il+3) * 33 + j], a3);
                }
                part += (a0 + a1) + (a2 + a3);
            }
            __syncthreads();
        }
        ws[WS_CP + blk * 64 + t] = part;
    } else {
        // fold Winf[i][j] = gamma_i * Win[i][j]; cin_j, din_j col-sums
        float cj[8], dj[8];
#pragma unroll
        for (int j = 0; j < 8; ++j) { cj[j] = 0.f; dj[j] = 0.f; }
        for (int k = 0; k < 32; ++k) {
            const int i = k * 64 + t;
            const float g = gamma[i], b = beta[i];
            float4 w0 = ld4(Win + (size_t)i * 8);
            float4 w1 = ld4(Win + (size_t)i * 8 + 4);
            st4(ws + WS_WINF + (size_t)i * 8,
                make_float4(g * w0.x, g * w0.y, g * w0.z, g * w0.w));
            st4(ws + WS_WINF + (size_t)i * 8 + 4,
                make_float4(g * w1.x, g * w1.y, g * w1.z, g * w1.w));
            cj[0] = fmaf(g, w0.x, cj[0]); cj[1] = fmaf(g, w0.y, cj[1]);
            cj[2] = fmaf(g, w0.z, cj[2]); cj[3] = fmaf(g, w0.w, cj[3]);
            cj[4] = fmaf(g, w1.x, cj[4]); cj[5] = fmaf(g, w1.y, cj[5]);
            cj[6] = fmaf(g, w1.z, cj[6]); cj[7] = fmaf(g, w1.w, cj[7]);
            dj[0] = fmaf(b, w0.x, dj[0]); dj[1] = fmaf(b, w0.y, dj[1]);
            dj[2] = fmaf(b, w0.z, dj[2]); dj[3] = fmaf(b, w0.w, dj[3]);
            dj[4] = fmaf(b, w1.x, dj[4]); dj[5] = fmaf(b, w1.y, dj[5]);
            dj[6] = fmaf(b, w1.z, dj[6]); dj[7] = fmaf(b, w1.w, dj[7]);
        }
#pragma unroll
        for (int off = 1; off < 64; off <<= 1) {
#pragma unroll
            for (int j = 0; j < 8; ++j) {
                cj[j] += __shfl_xor(cj[j], off, 64);
                dj[j] += __shfl_xor(dj[j], off, 64);
            }
        }
        if (t == 0) {
#pragma unroll
            for (int j = 0; j < 8; ++j) {
                ws[WS_CIN + j] = cj[j];
                ws[WS_DIN + j] = dj[j] + b_in[j];
            }
        }
    }
}

// ---------------------------------------------------------------------------
// K1: 16 rows/block (1024 blocks, 16 waves/CU). Each wave owns a 512-col
// slice; lane loads float4 at lane*4 -> every load instr covers 1 KB
// contiguous. winf slice (64 regs) reused over 16 rows. Per row: 10 partials
// in one 16-value split-butterfly -> LDS; 1 barrier; 16 threads finalize.
// ---------------------------------------------------------------------------
__global__ __launch_bounds__(256, 4) void k1_ln_u(
    const float* __restrict__ x, float* __restrict__ ws)
{
    __shared__ float red[16][4][12];
    const int t = threadIdx.x;
    const int wv = t >> 6, lane = t & 63;
    const int row0 = blockIdx.x * 16;
    const int c0 = wv * 512 + lane * 4;        // cols c0..c0+3 and c0+256..+259

    // winf for this lane's 8 i-values: [rep][di][j] = winf[rep*32 + di*8 + j]
    float winf[64];
#pragma unroll
    for (int rep = 0; rep < 2; ++rep) {
        const int ib = c0 + rep * 256;
#pragma unroll
        for (int q = 0; q < 8; ++q) {
            float4 v = ld4(ws + WS_WINF + (size_t)ib * 8 + q * 4);
            winf[rep*32 + q*4 + 0] = v.x; winf[rep*32 + q*4 + 1] = v.y;
            winf[rep*32 + q*4 + 2] = v.z; winf[rep*32 + q*4 + 3] = v.w;
        }
    }
    float4 xa = ld4(x + (size_t)row0 * D_MODEL + c0);
    float4 xb = ld4(x + (size_t)row0 * D_MODEL + c0 + 256);
#pragma unroll 1
    for (int rr = 0; rr < 16; ++rr) {
        float xc[8];
        xc[0]=xa.x; xc[1]=xa.y; xc[2]=xa.z; xc[3]=xa.w;
        xc[4]=xb.x; xc[5]=xb.y; xc[6]=xb.z; xc[7]=xb.w;
        if (rr < 15) {
            const float* xr = x + (size_t)(row0 + rr + 1) * D_MODEL + c0;
            xa = ld4(xr);
            xb = ld4(xr + 256);
        }
        float vals[16];
#pragma unroll
        for (int v = 0; v < 16; ++v) vals[v] = 0.f;
#pragma unroll
        for (int rep = 0; rep < 2; ++rep) {
#pragma unroll
            for (int di = 0; di < 4; ++di) {
                const float xi = xc[rep*4 + di];
                vals[0] += xi;
                vals[1] = fmaf(xi, xi, vals[1]);
#pragma unroll
                for (int j = 0; j < 8; ++j)
                    vals[2+j] = fmaf(xi, winf[rep*32 + di*8 + j], vals[2+j]);
            }
        }
        // 16-value split-butterfly over 64 lanes
        int count = 16;
#pragma unroll
        for (int step = 1; step <= 32; step <<= 1) {
            if (count > 1) {
                const int half = count >> 1;
                const bool up = (lane & step) != 0;
#pragma unroll
                for (int k = 0; k < 8; ++k) {
                    if (k < half) {
                        float send = vals[up ? k : k + half];
                        float keep = vals[up ? k + half : k];
                        vals[k] = keep + __shfl_xor(send, step, 64);
                    }
                }
                count = half;
            } else {
                vals[0] += __shfl_xor(vals[0], step, 64);
            }
        }
        if (lane < 16) {
            const int v = bitrev4(lane);
            if (v < 10) red[rr][wv][v] = vals[0];
        }
    }
    __syncthreads();
    if (t < 16) {
        const int grow = row0 + t;
        float s_ = 0.f, q_ = 0.f, uraw[8];
#pragma unroll
        for (int j = 0; j < 8; ++j) uraw[j] = 0.f;
#pragma unroll
        for (int w = 0; w < 4; ++w) {
            s_ += red[t][w][0];
            q_ += red[t][w][1];
#pragma unroll
            for (int j = 0; j < 8; ++j) uraw[j] += red[t][w][2 + j];
        }
        const float mu = s_ * (1.f / D_MODEL);
        const float var = q_ * (1.f / D_MODEL) - mu * mu;
        const float rs = rsqrtf(var + EPSF);
        const int bb = grow >> 12, s0 = grow & 4095;
#pragma unroll
        for (int j = 0; j < 8; ++j) {
            const float u = fmaf(rs, fmaf(-mu, ws[WS_CIN + j], uraw[j]),
                                 ws[WS_DIN + j]);
            ws[WS_UT + ((size_t)bb * 8 + j) * 4096 + s0] = u;
        }
        ws[WS_MU1 + grow] = mu;
        ws[WS_RSIG1 + grow] = rs;
    }
}

// ---------------------------------------------------------------------------
// K2: blocks 0..31: decay scan per (b,r); block 32: finalize c/d col-sums.
// ---------------------------------------------------------------------------
__global__ __launch_bounds__(64) void k2_scan(
    const float* __restrict__ logit, const float* __restrict__ bd,
    float* __restrict__ ws)
{
    const int t = threadIdx.x;
    const int blk = blockIdx.x;
    if (blk == 32) {
        const int j = t & 31;
        float s = 0.f;
#pragma unroll
        for (int g = 0; g < 8; ++g) s += ws[WS_CP + g * 64 + (t < 32 ? j : 32 + j)];
        if (t < 32) ws[WS_C + j] = s;
        else        ws[WS_D + j] = s + bd[j];
        return;
    }
    const int b = blk >> 3, r = blk & 7;
    const float a = 1.f / (1.f + expf(-logit[r]));
    float* u = ws + WS_UT + ((size_t)b * 8 + r) * 4096 + t * 64;
    float v[64];
#pragma unroll
    for (int q = 0; q < 16; ++q) {
        float4 w = ld4(u + q * 4);
        v[q*4]=w.x; v[q*4+1]=w.y; v[q*4+2]=w.z; v[q*4+3]=w.w;
    }
    float c = 0.f;
#pragma unroll
    for (int k = 0; k < 64; ++k) { c = fmaf(a, c, v[k]); v[k] = c; }
    float A = a;
#pragma unroll
    for (int i = 0; i < 6; ++i) A *= A;   // a^64
    float Bv = c, Aa = A;
#pragma unroll
    for (int off = 1; off < 64; off <<= 1) {
        float Ap = __shfl_up(Aa, off, 64);
        float Bp = __shfl_up(Bv, off, 64);
        if (t >= off) { Bv = fmaf(Aa, Bp, Bv); Aa *= Ap; }
    }
    float P = __shfl_up(Bv, 1, 64);
    if (t == 0) P = 0.f;
    float f = a * P;
#pragma unroll
    for (int k = 0; k < 64; ++k) { v[k] += f; f *= a; }
#pragma unroll
    for (int q = 0; q < 16; ++q)
        st4(u + q * 4, make_float4(v[q*4], v[q*4+1], v[q*4+2], v[q*4+3]));
}

// ---------------------------------------------------------------------------
// K3: fused tail, 8 rows/block, col-owned phase A. (unchanged this round)
// ---------------------------------------------------------------------------
__global__ __launch_bounds__(256, 2) void k3_fused(
    const float* __restrict__ x, const float* __restrict__ gamma,
    const float* __restrict__ beta, const float* __restrict__ Wout,
    const float* __restrict__ b_out, const float* __restrict__ Dsk,
    const float* __restrict__ Wu, const float* __restrict__ bu,
    float* __restrict__ out, float* __restrict__ ws)
{
    __shared__ float Y[8 * 2048];   // 64 KiB: x2 rows
    __shared__ float sh_h[8][8];
    __shared__ float smu1[8], srs1[8];
    __shared__ float smu2[8], srs2[8];
    __shared__ float red2[16][4];
    __shared__ float shf[8 * 32];
    const int t = threadIdx.x;
    const int blk = blockIdx.x;
    const int row0 = blk * 8;
    const int wv = t >> 6, lane = t & 63;

    if (t < 64) {
        const int r_ = t >> 3, j_ = t & 7;
        const int grow = row0 + r_;
        const int bb = grow >> 12, s = grow & 4095;
        sh_h[r_][j_] = ws[WS_UT + ((size_t)bb * 8 + j_) * 4096 + s];
        if (j_ == 0) {
            smu1[r_] = ws[WS_MU1 + grow];
            srs1[r_] = ws[WS_RSIG1 + grow];
        }
    }
    __syncthreads();

    // copy h to regs (broadcast b128 LDS reads)
    float hreg[64];
#pragma unroll
    for (int r = 0; r < 8; ++r) {
        float4 h0 = ld4(&sh_h[r][0]);
        float4 h1 = ld4(&sh_h[r][4]);
        hreg[r*8+0]=h0.x; hreg[r*8+1]=h0.y; hreg[r*8+2]=h0.z; hreg[r*8+3]=h0.w;
        hreg[r*8+4]=h1.x; hreg[r*8+5]=h1.y; hreg[r*8+6]=h1.z; hreg[r*8+7]=h1.w;
    }

    float sum[8], ssq[8];
#pragma unroll
    for (int r = 0; r < 8; ++r) { sum[r] = 0.f; ssq[r] = 0.f; }

#pragma unroll 1
    for (int pass = 0; pass < 2; ++pass) {
        const int c = pass * 1024 + t * 4;
        const float4 g = ld4(gamma + c), bt = ld4(beta + c);
        const float4 bo = ld4(b_out + c), dk = ld4(Dsk + c);
        float4 wo[8];
#pragma unroll
        for (int j = 0; j < 8; ++j) wo[j] = ld4(Wout + (size_t)j * D_MODEL + c);
#pragma unroll
        for (int r = 0; r < 8; ++r) {
            const float4 xv = ld4(x + (size_t)(row0 + r) * D_MODEL + c);
            const float mu1 = smu1[r], rs1 = srs1[r];
            float4 acc = bo;
#pragma unroll
            for (int j = 0; j < 8; ++j) {
                const float hj = hreg[r*8 + j];
                acc.x = fmaf(hj, wo[j].x, acc.x);
                acc.y = fmaf(hj, wo[j].y, acc.y);
                acc.z = fmaf(hj, wo[j].z, acc.z);
                acc.w = fmaf(hj, wo[j].w, acc.w);
            }
            float4 xn;
            xn.x = fmaf((xv.x - mu1) * rs1, g.x, bt.x);
            xn.y = fmaf((xv.y - mu1) * rs1, g.y, bt.y);
            xn.z = fmaf((xv.z - mu1) * rs1, g.z, bt.z);
            xn.w = fmaf((xv.w - mu1) * rs1, g.w, bt.w);
            acc.x = fmaf(xn.x, dk.x, acc.x);
            acc.y = fmaf(xn.y, dk.y, acc.y);
            acc.z = fmaf(xn.z, dk.z, acc.z);
            acc.w = fmaf(xn.w, dk.w, acc.w);
            float4 x2;
            x2.x = xv.x + acc.x; x2.y = xv.y + acc.y;
            x2.z = xv.z + acc.z; x2.w = xv.w + acc.w;
            st4(&Y[r * 2048 + c], x2);
            sum[r] += x2.x + x2.y + x2.z + x2.w;
            ssq[r] = fmaf(x2.x, x2.x, ssq[r]); ssq[r] = fmaf(x2.y, x2.y, ssq[r]);
            ssq[r] = fmaf(x2.z, x2.z, ssq[r]); ssq[r] = fmaf(x2.w, x2.w, ssq[r]);
        }
    }
    // batched LN2 reduce: 16 values (sum[0..8), ssq[0..8))
    {
        float vals[16];
#pragma unroll
        for (int r = 0; r < 8; ++r) { vals[r] = sum[r]; vals[8+r] = ssq[r]; }
        int count = 16;
#pragma unroll
        for (int step = 1; step <= 32; step <<= 1) {
            if (count > 1) {
                const int half = count >> 1;
                const bool up = (lane & step) != 0;
#pragma unroll
                for (int k = 0; k < 8; ++k) {
                    if (k < half) {
                        float send = vals[up ? k : k + half];
                        float keep = vals[up ? k + half : k];
                        vals[k] = keep + __shfl_xor(send, step, 64);
                    }
                }
                count = half;
            } else {
                vals[0] += __shfl_xor(vals[0], step, 64);
            }
        }
        if (lane < 16) red2[bitrev4(lane)][wv] = vals[0];
    }
    __syncthreads();
    if (t < 8) {
        float s_ = red2[t][0] + red2[t][1] + red2[t][2] + red2[t][3];
        float q_ = red2[8+t][0] + red2[8+t][1] + red2[8+t][2] + red2[8+t][3];
        const float mu2 = s_ * (1.f / D_MODEL);
        const float var = q_ * (1.f / D_MODEL) - mu2 * mu2;
        smu2[t] = mu2;
        srs2[t] = rsqrtf(var + EPSF);
    }
    __syncthreads();

    // Phase B: wave wv owns j-octet [8wv, 8wv+8)
    const int jb = wv * 8;
    float p[64];
#pragma unroll
    for (int v = 0; v < 64; ++v) p[v] = 0.f;
    float4 wb[8], wbn[8];
#pragma unroll
    for (int jj = 0; jj < 8; ++jj)
        wb[jj] = ld4(ws + WS_WDT + (size_t)(jb + jj) * 2048 + lane * 4);
#pragma unroll 1
    for (int q = 0; q < 8; ++q) {
        const int ip = q * 256 + lane * 4;
        if (q < 7) {
#pragma unroll
            for (int jj = 0; jj < 8; ++jj)
                wbn[jj] = ld4(ws + WS_WDT + (size_t)(jb + jj) * 2048 + ip + 256);
        }
        float4 yv[8];
#pragma unroll
        for (int rr = 0; rr < 8; ++rr) yv[rr] = ld4(&Y[rr * 2048 + ip]);
#pragma unroll
        for (int jj = 0; jj < 8; ++jj) {
#pragma unroll
            for (int rr = 0; rr < 8; ++rr) {
                p[rr*8+jj] = fmaf(yv[rr].x, wb[jj].x, p[rr*8+jj]);
                p[rr*8+jj] = fmaf(yv[rr].y, wb[jj].y, p[rr*8+jj]);
                p[rr*8+jj] = fmaf(yv[rr].z, wb[jj].z, p[rr*8+jj]);
                p[rr*8+jj] = fmaf(yv[rr].w, wb[jj].w, p[rr*8+jj]);
            }
        }
#pragma unroll
        for (int jj = 0; jj < 8; ++jj) wb[jj] = wbn[jj];
    }
    // split-butterfly reduce: lane ends with total for v = bitrev6(lane)
    {
        int count = 64;
#pragma unroll
        for (int step = 1; step <= 32; step <<= 1) {
            const int half = count >> 1;
            const bool up = (lane & step) != 0;
#pragma unroll
            for (int k = 0; k < 32; ++k) {
                if (k < half) {
                    float send = p[up ? k : k + half];
                    float keep = p[up ? k + half : k];
                    p[k] = keep + __shfl_xor(send, step, 64);
                }
            }
            count = half;
        }
    }
    {
        const int v = bitrev6(lane);
        const int r_ = v >> 3, j_ = v & 7;
        const float mu2r = smu2[r_], rs2r = srs2[r_];
        const float cj = ws[WS_C + jb + j_], dj = ws[WS_D + jb + j_];
        shf[r_ * 32 + jb + j_] =
            fmaxf(0.f, fmaf(rs2r, fmaf(-mu2r, cj, p[0]), dj));
    }
    __syncthreads();

    // Phase C: thread owns cols c0=t*4 and c0+1024 for all 8 rows
    const int c0 = t * 4;
    float4 a0[8], a1[8];
    const float4 bu0 = ld4(bu + c0), bu1 = ld4(bu + 1024 + c0);
#pragma unroll
    for (int rr = 0; rr < 8; ++rr) {
        float4 y0 = ld4(&Y[rr * 2048 + c0]);
        float4 y1 = ld4(&Y[rr * 2048 + 1024 + c0]);
        a0[rr] = make_float4(y0.x + bu0.x, y0.y + bu0.y, y0.z + bu0.z, y0.w + bu0.w);
        a1[rr] = make_float4(y1.x + bu1.x, y1.y + bu1.y, y1.z + bu1.z, y1.w + bu1.w);
    }
    float4 w0[4], w1[4], w0n[4], w1n[4];
#pragma unroll
    for (int jj = 0; jj < 4; ++jj) {
        w0[jj] = ld4(Wu + (size_t)jj * D_MODEL + c0);
        w1[jj] = ld4(Wu + (size_t)jj * D_MODEL + 1024 + c0);
    }
#pragma unroll 1
    for (int jc = 0; jc < 8; ++jc) {
        if (jc < 7) {
#pragma unroll
            for (int jj = 0; jj < 4; ++jj) {
                w0n[jj] = ld4(Wu + (size_t)((jc+1)*4 + jj) * D_MODEL + c0);
                w1n[jj] = ld4(Wu + (size_t)((jc+1)*4 + jj) * D_MODEL + 1024 + c0);
            }
        }
        float4 hq[8];
#pragma unroll
        for (int rr = 0; rr < 8; ++rr) hq[rr] = ld4(&shf[rr * 32 + jc * 4]);
#pragma unroll
        for (int jj = 0; jj < 4; ++jj) {
#pragma unroll
            for (int rr = 0; rr < 8; ++rr) {
                const float hval = (jj == 0) ? hq[rr].x : (jj == 1) ? hq[rr].y
                                 : (jj == 2) ? hq[rr].z : hq[rr].w;
                a0[rr].x = fmaf(hval, w0[jj].x, a0[rr].x);
                a0[rr].y = fmaf(hval, w0[jj].y, a0[rr].y);
                a0[rr].z = fmaf(hval, w0[jj].z, a0[rr].z);
                a0[rr].w = fmaf(hval, w0[jj].w, a0[rr].w);
                a1[rr].x = fmaf(hval, w1[jj].x, a1[rr].x);
                a1[rr].y = fmaf(hval, w1[jj].y, a1[rr].y);
                a1[rr].z = fmaf(hval, w1[jj].z, a1[rr].z);
                a1[rr].w = fmaf(hval, w1[jj].w, a1[rr].w);
            }
        }
#pragma unroll
        for (int jj = 0; jj < 4; ++jj) { w0[jj] = w0n[jj]; w1[jj] = w1n[jj]; }
    }
#pragma unroll
    for (int rr = 0; rr < 8; ++rr) {
        float* orow = out + (size_t)(row0 + rr) * D_MODEL;
        st4(orow + c0, a0[rr]);
        st4(orow + 1024 + c0, a1[rr]);
    }
}

// ---------------------------------------------------------------------------
extern "C" void kernel_launch(void* const* d_in, const int* in_sizes, int n_in,
                              void* d_out, int out_size, void* d_ws, size_t ws_size,
                              hipStream_t stream) {
    const float* x      = (const float*)d_in[0];
    const float* gamma  = (const float*)d_in[1];
    const float* beta   = (const float*)d_in[2];
    const float* Win    = (const float*)d_in[3];
    const float* b_in   = (const float*)d_in[4];
    const float* logit  = (const float*)d_in[5];
    const float* Wout   = (const float*)d_in[6];
    const float* b_out  = (const float*)d_in[7];
    const float* Dsk    = (const float*)d_in[8];
    const float* Wd     = (const float*)d_in[9];
    const float* bd     = (const float*)d_in[10];
    const float* Wu     = (const float*)d_in[11];
    const float* bu     = (const float*)d_in[12];
    float* out = (float*)d_out;
    float* ws  = (float*)d_ws;

    hipLaunchKernelGGL(k0_prep, dim3(9),    dim3(64),  0, stream,
                       Win, b_in, Wd, gamma, beta, bd, ws);
    hipLaunchKernelGGL(k1_ln_u, dim3(1024), dim3(256), 0, stream, x, ws);
    hipLaunchKernelGGL(k2_scan, dim3(33),   dim3(64),  0, stream, logit, bd, ws);
    hipLaunchKernelGGL(k3_fused, dim3(2048), dim3(256), 0, stream,
                       x, gamma, beta, Wout, b_out, Dsk, Wu, bu, out, ws);
}